// Round 4
// baseline (307.251 us; speedup 1.0000x reference)
//
#include <hip/hip_runtime.h>
#include <hip/hip_cooperative_groups.h>

namespace cg = cooperative_groups;

// Problem constants
#define Bn  4
#define Cc  64      // channels
#define ICc 32      // inner channels
#define Hh  128
#define Ww  128
#define Nn  (Hh*Ww)     // 16384
#define Hp  (Hh/2)      // 64 pooled rows
#define Wp  (Ww/2)      // 64 pooled cols
#define Mm  (Hp*Wp)     // 4096 pooled positions
#define Sg  8           // gram m-split (8 slices of 512)

// Shared scratch reused across phases (~19.6 KB -> 2+ blocks/CU fine)
struct SharedMem {
    float sw[ICc * Cc];   // phase 1 weights
    float sb[ICc];
    float red[4][64];     // phase 2 cross-wave reduce
    float sA[ICc * ICc];  // phase 3 summed gram
    float sT[16 * ICc];
    float sM[16 * Cc];
    float sv[16];
};

// ---------------------------------------------------------------------------
// Phase 1: conv1x1 + 2x2 maxpool for phi(ref) and g(ref_align).
// bid: inp = bid&1, b = (bid>>1)&3, ph = bid>>3  (512 blocks)
// tid: icg = tid>>7 (16-IC half), pw = (tid&127)>>1, r = tid&1.
// Both IC halves read the same 2 input rows -> L1-shared; image read ONCE.
// ---------------------------------------------------------------------------
__device__ void phase1(SharedMem& sm, int bid, int tid,
                       const float* __restrict__ ref, const float* __restrict__ ref_align,
                       const float* __restrict__ phi_w, const float* __restrict__ phi_b,
                       const float* __restrict__ g_w,   const float* __restrict__ g_b,
                       float* __restrict__ P, float* __restrict__ G)
{
    const int inp = bid & 1;
    const int b   = (bid >> 1) & 3;
    const int ph  = bid >> 3;
    const float* in   = inp ? ref_align : ref;
    const float* wmat = inp ? g_w : phi_w;
    const float* bias = inp ? g_b : phi_b;
    float* outp       = inp ? G : P;

    for (int idx = tid; idx < ICc * Cc; idx += 256) sm.sw[idx] = wmat[idx];
    if (tid < ICc) sm.sb[tid] = bias[tid];
    __syncthreads();

    const int icb = (tid >> 7) * 16;    // 0 or 16
    const int t   = tid & 127;
    const int pw  = t >> 1;
    const int r   = t & 1;
    const int hh  = 2 * ph + r;
    const float2* xrow = (const float2*)(in + ((size_t)b * Cc * Hh + hh) * Ww);
    const int cs2 = (Hh * Ww) / 2;

    float acc0[16], acc1[16];
    #pragma unroll
    for (int i = 0; i < 16; ++i) { acc0[i] = sm.sb[icb + i]; acc1[i] = sm.sb[icb + i]; }

    #pragma unroll 8
    for (int c = 0; c < Cc; ++c) {
        float2 v = xrow[c * cs2 + pw];
        #pragma unroll
        for (int i = 0; i < 16; ++i) {
            float w = sm.sw[(icb + i) * Cc + c];
            acc0[i] = fmaf(w, v.x, acc0[i]);
            acc1[i] = fmaf(w, v.y, acc1[i]);
        }
    }

    const int m = ph * Wp + pw;
    #pragma unroll
    for (int i = 0; i < 16; ++i) {
        float mx = fmaxf(acc0[i], acc1[i]);
        mx = fmaxf(mx, __shfl_xor(mx, 1, 64));   // tid^1 = same pw, other row
        if (r == 0) outp[((size_t)(b * ICc + icb + i)) * Mm + m] = mx;
    }
}

// ---------------------------------------------------------------------------
// Phase 2: gram partials. bid: ig = bid&15 (2 i-rows), b = (bid>>4)&3,
// sl = bid>>6 (slice of 512 m). Thread owns ONE float2 m-pair; accumulates
// a{0,1}[32]; wave butterfly then lane-0 -> LDS -> 64-thread combine.
// Apart[b][sl][i][j].  P re-read 16x -> 35 MB total.
// ---------------------------------------------------------------------------
__device__ void phase2(SharedMem& sm, int bid, int tid,
                       const float* __restrict__ P, const float* __restrict__ G,
                       float* __restrict__ Apart)
{
    const int ig = bid & 15;
    const int b  = (bid >> 4) & 3;
    const int sl = bid >> 6;            // 0..7
    const int i0 = ig * 2;
    const int m2 = sl * 256 + tid;      // float2 index
    const int cm2 = Mm / 2;
    const float2* Gb = (const float2*)(G + (size_t)b * ICc * Mm);
    const float2* Pb = (const float2*)(P + (size_t)b * ICc * Mm);

    const float2 g0 = Gb[(i0 + 0) * cm2 + m2];
    const float2 g1 = Gb[(i0 + 1) * cm2 + m2];

    float a0[ICc], a1[ICc];
    #pragma unroll 8
    for (int j = 0; j < ICc; ++j) {
        float2 p = Pb[j * cm2 + m2];
        a0[j] = fmaf(g0.x, p.x, g0.y * p.y);
        a1[j] = fmaf(g1.x, p.x, g1.y * p.y);
    }

    #pragma unroll
    for (int j = 0; j < ICc; ++j) {
        #pragma unroll
        for (int off = 32; off > 0; off >>= 1) {
            a0[j] += __shfl_xor(a0[j], off, 64);
            a1[j] += __shfl_xor(a1[j], off, 64);
        }
    }

    const int lane = tid & 63, wid = tid >> 6;
    if (lane == 0) {
        #pragma unroll
        for (int j = 0; j < ICc; ++j) {
            sm.red[wid][j]       = a0[j];
            sm.red[wid][32 + j]  = a1[j];
        }
    }
    __syncthreads();

    if (tid < 64) {
        float s = sm.red[0][tid] + sm.red[1][tid] + sm.red[2][tid] + sm.red[3][tid];
        Apart[((size_t)(b * Sg + sl)) * (ICc * ICc) + (i0 + (tid >> 5)) * ICc + (tid & 31)] = s;
    }
    __syncthreads();
}

// ---------------------------------------------------------------------------
// Phase 3: combine + apply. bid: nt = bid&31 (256-f2 tile), b = (bid>>5)&3,
// og = bid>>7 (16-output group). Prologue builds 16 rows of
// M'[o,c] = (W_w @ (A/N) @ theta_w)[o,c] + (o==c), v[o] = ... + W_b[o].
// Main: out[o, n] = sum_c M'[o,c] x[c,n] + v[o].  x read 4x -> 67 MB.
// ---------------------------------------------------------------------------
__device__ void phase3(SharedMem& sm, int bid, int tid,
                       const float* __restrict__ x, const float* __restrict__ Apart,
                       const float* __restrict__ theta_w, const float* __restrict__ theta_b,
                       const float* __restrict__ W_w,     const float* __restrict__ W_b,
                       float* __restrict__ out)
{
    const int nt = bid & 31;
    const int b  = (bid >> 5) & 3;
    const int ob = (bid >> 7) * 16;

    const float* Ab = Apart + (size_t)b * Sg * ICc * ICc;
    for (int idx = tid; idx < ICc * ICc; idx += 256) {
        float s = 0.f;
        #pragma unroll
        for (int k = 0; k < Sg; ++k) s += Ab[k * ICc * ICc + idx];
        sm.sA[idx] = s;
    }
    __syncthreads();

    for (int idx = tid; idx < 16 * ICc; idx += 256) {
        const int ol = idx >> 5, j = idx & 31;
        const float* wr = W_w + (ob + ol) * ICc;
        float t = 0.f;
        #pragma unroll
        for (int i = 0; i < ICc; ++i) t = fmaf(wr[i], sm.sA[i * ICc + j], t);
        sm.sT[idx] = t;
    }
    __syncthreads();

    const float invN = 1.f / (float)Nn;
    for (int idx = tid; idx < 16 * Cc; idx += 256) {
        const int ol = idx >> 6, c = idx & 63;
        float s = 0.f;
        #pragma unroll
        for (int j = 0; j < ICc; ++j) s = fmaf(sm.sT[ol * ICc + j], theta_w[j * Cc + c], s);
        sm.sM[idx] = s * invN + ((ob + ol) == c ? 1.f : 0.f);
    }
    if (tid < 16) {
        float v = 0.f;
        #pragma unroll
        for (int j = 0; j < ICc; ++j) v = fmaf(sm.sT[tid * ICc + j], theta_b[j], v);
        sm.sv[tid] = v * invN + W_b[ob + tid];
    }
    __syncthreads();

    const int n2 = nt * 256 + tid;
    const float2* xb = (const float2*)(x + (size_t)b * Cc * Nn);
    float2*       ob2 = (float2*)(out + (size_t)b * Cc * Nn);

    float ax[16], ay[16];
    #pragma unroll
    for (int i = 0; i < 16; ++i) { ax[i] = sm.sv[i]; ay[i] = sm.sv[i]; }

    #pragma unroll 8
    for (int c = 0; c < Cc; ++c) {
        float2 xv = xb[c * (Nn / 2) + n2];
        #pragma unroll
        for (int i = 0; i < 16; ++i) {
            float w = sm.sM[i * Cc + c];     // wave-broadcast, conflict-free
            ax[i] = fmaf(w, xv.x, ax[i]);
            ay[i] = fmaf(w, xv.y, ay[i]);
        }
    }

    #pragma unroll
    for (int i = 0; i < 16; ++i) {
        float2 o2; o2.x = ax[i]; o2.y = ay[i];
        ob2[(ob + i) * (Nn / 2) + n2] = o2;
    }
}

// ---------------------------------------------------------------------------
// Cooperative mega-kernel: 512 blocks x 256 threads, 2 blocks/CU co-resident.
// ---------------------------------------------------------------------------
__global__ __launch_bounds__(256, 2) void mega_kernel(
    const float* __restrict__ target, const float* __restrict__ ref,
    const float* __restrict__ ref_align,
    const float* __restrict__ theta_w, const float* __restrict__ theta_b,
    const float* __restrict__ phi_w,   const float* __restrict__ phi_b,
    const float* __restrict__ g_w,     const float* __restrict__ g_b,
    const float* __restrict__ W_w,     const float* __restrict__ W_b,
    float* __restrict__ P, float* __restrict__ G, float* __restrict__ Apart,
    float* __restrict__ out)
{
    __shared__ SharedMem sm;
    cg::grid_group grid = cg::this_grid();
    const int bid = blockIdx.x, tid = threadIdx.x;

    phase1(sm, bid, tid, ref, ref_align, phi_w, phi_b, g_w, g_b, P, G);
    grid.sync();
    phase2(sm, bid, tid, P, G, Apart);
    grid.sync();
    phase3(sm, bid, tid, target, Apart, theta_w, theta_b, W_w, W_b, out);
}

// Fallback wrappers (non-cooperative, 3 launches, same partitioning)
__global__ __launch_bounds__(256, 2) void k_conv(
    const float* __restrict__ ref, const float* __restrict__ ref_align,
    const float* __restrict__ phi_w, const float* __restrict__ phi_b,
    const float* __restrict__ g_w,   const float* __restrict__ g_b,
    float* __restrict__ P, float* __restrict__ G)
{
    __shared__ SharedMem sm;
    phase1(sm, blockIdx.x, threadIdx.x, ref, ref_align, phi_w, phi_b, g_w, g_b, P, G);
}

__global__ __launch_bounds__(256, 2) void k_gram(
    const float* __restrict__ P, const float* __restrict__ G, float* __restrict__ Apart)
{
    __shared__ SharedMem sm;
    phase2(sm, blockIdx.x, threadIdx.x, P, G, Apart);
}

__global__ __launch_bounds__(256, 2) void k_apply(
    const float* __restrict__ x, const float* __restrict__ Apart,
    const float* __restrict__ theta_w, const float* __restrict__ theta_b,
    const float* __restrict__ W_w,     const float* __restrict__ W_b,
    float* __restrict__ out)
{
    __shared__ SharedMem sm;
    phase3(sm, blockIdx.x, threadIdx.x, x, Apart, theta_w, theta_b, W_w, W_b, out);
}

// ---------------------------------------------------------------------------
extern "C" void kernel_launch(void* const* d_in, const int* in_sizes, int n_in,
                              void* d_out, int out_size, void* d_ws, size_t ws_size,
                              hipStream_t stream) {
    const float* target    = (const float*)d_in[0];
    const float* ref       = (const float*)d_in[1];
    const float* ref_align = (const float*)d_in[2];
    const float* theta_w   = (const float*)d_in[3];
    const float* theta_b   = (const float*)d_in[4];
    const float* phi_w     = (const float*)d_in[5];
    const float* phi_b     = (const float*)d_in[6];
    const float* g_w       = (const float*)d_in[7];
    const float* g_b       = (const float*)d_in[8];
    const float* W_w       = (const float*)d_in[9];
    const float* W_b       = (const float*)d_in[10];
    float* out = (float*)d_out;

    // workspace (floats): P[B*IC*M] | G[B*IC*M] | Apart[B*Sg*IC*IC]
    float* ws    = (float*)d_ws;
    float* P     = ws;
    float* G     = P + (size_t)Bn * ICc * Mm;
    float* Apart = G + (size_t)Bn * ICc * Mm;

    void* args[] = {
        (void*)&target, (void*)&ref, (void*)&ref_align,
        (void*)&theta_w, (void*)&theta_b, (void*)&phi_w, (void*)&phi_b,
        (void*)&g_w, (void*)&g_b, (void*)&W_w, (void*)&W_b,
        (void*)&P, (void*)&G, (void*)&Apart, (void*)&out
    };
    hipError_t e = hipLaunchCooperativeKernel(
        reinterpret_cast<void*>(mega_kernel), dim3(512), dim3(256), args, 0, stream);

    if (e != hipSuccess) {
        // non-cooperative fallback: same phases, explicit launch ordering
        k_conv<<<512, 256, 0, stream>>>(ref, ref_align, phi_w, phi_b, g_w, g_b, P, G);
        k_gram<<<512, 256, 0, stream>>>(P, G, Apart);
        k_apply<<<512, 256, 0, stream>>>(target, Apart, theta_w, theta_b, W_w, W_b, out);
    }
}

// Round 5
// 147.649 us; speedup vs baseline: 2.0810x; 2.0810x over previous
//
#include <hip/hip_runtime.h>

// Problem constants
#define Bn  4
#define Cc  64      // channels
#define ICc 32      // inner channels
#define Hh  128
#define Ww  128
#define Nn  (Hh*Ww)     // 16384
#define Hp  (Hh/2)      // 64 pooled rows
#define Wp  (Ww/2)      // 64 pooled cols
#define Mm  (Hp*Wp)     // 4096 pooled positions
#define Sg  4           // gram m-split (4 slices of 1024)

// ---------------------------------------------------------------------------
// Kernel 1: conv1x1 + 2x2 maxpool for phi(ref) and g(ref_align).
// grid (Hp, B, 4): z&1 = input select, z>>1 = 16-IC half. block 256:
// tid>>7 = 8-IC octet within the half, t=tid&127: pw=t>>1, r=t&1.
// Image read 2x total (L3-served second pass). 1024 blocks x 4 waves
// = 16 waves/CU = 4/SIMD.
// ---------------------------------------------------------------------------
__global__ __launch_bounds__(256) void conv_pool_kernel(
    const float* __restrict__ ref, const float* __restrict__ ref_align,
    const float* __restrict__ phi_w, const float* __restrict__ phi_b,
    const float* __restrict__ g_w,   const float* __restrict__ g_b,
    float* __restrict__ P, float* __restrict__ G)
{
    const int z   = blockIdx.z;
    const int inp = z & 1;
    const int ich = (z >> 1) * 16;      // 0 or 16
    const float* in   = inp ? ref_align : ref;
    const float* wmat = (inp ? g_w : phi_w) + ich * Cc;
    const float* bias = (inp ? g_b : phi_b) + ich;
    float* outp       = inp ? G : P;

    __shared__ float sw[16 * Cc];
    __shared__ float sb[16];
    for (int idx = threadIdx.x; idx < 16 * Cc; idx += 256) sw[idx] = wmat[idx];
    if (threadIdx.x < 16) sb[threadIdx.x] = bias[threadIdx.x];
    __syncthreads();

    const int icq = (threadIdx.x >> 7) * 8;   // 0 or 8 within the 16-IC half
    const int t   = threadIdx.x & 127;
    const int pw  = t >> 1;
    const int r   = t & 1;
    const int ph  = blockIdx.x;
    const int b   = blockIdx.y;
    const int hh  = 2 * ph + r;

    const float2* xrow = (const float2*)(in + ((size_t)b * Cc * Hh + hh) * Ww);
    const int cs2 = (Hh * Ww) / 2;

    float acc0[8], acc1[8];
    #pragma unroll
    for (int i = 0; i < 8; ++i) { acc0[i] = sb[icq + i]; acc1[i] = sb[icq + i]; }

    #pragma unroll 8
    for (int c = 0; c < Cc; ++c) {
        float2 v = xrow[c * cs2 + pw];
        #pragma unroll
        for (int i = 0; i < 8; ++i) {
            float w = sw[(icq + i) * Cc + c];
            acc0[i] = fmaf(w, v.x, acc0[i]);
            acc1[i] = fmaf(w, v.y, acc1[i]);
        }
    }

    const int m = ph * Wp + pw;
    #pragma unroll
    for (int i = 0; i < 8; ++i) {
        float mx = fmaxf(acc0[i], acc1[i]);
        mx = fmaxf(mx, __shfl_xor(mx, 1, 64));   // vertical max: pair lanes same wave
        if (r == 0) outp[((size_t)(b * ICc + ich + icq + i)) * Mm + m] = mx;
    }
}

// ---------------------------------------------------------------------------
// Kernel 2: partial gram via float4.
// Apart[b,s,i,j] = sum_{m in slice s} G[b,i,m]*P[b,j,m].
// grid (IC, B, Sg) = 512 blocks, block 256; thread owns ONE float4 m-quad
// (slice = 1024 m = 256 quads). 33 dwordx4 loads + 128 FMA per thread,
// then 6-level wave butterfly + LDS cross-wave combine.
// ---------------------------------------------------------------------------
__global__ __launch_bounds__(256) void gram_kernel(
    const float* __restrict__ P, const float* __restrict__ G,
    float* __restrict__ Apart)
{
    const int i = blockIdx.x, b = blockIdx.y, s = blockIdx.z;
    const int cm4 = Mm / 4;
    const int q   = s * 256 + threadIdx.x;    // float4 index within the batch row
    const float4* G4 = (const float4*)(G + (size_t)b * ICc * Mm);
    const float4* P4 = (const float4*)(P + (size_t)b * ICc * Mm);

    const float4 g = G4[i * cm4 + q];

    float acc[ICc];
    #pragma unroll 8
    for (int j = 0; j < ICc; ++j) {
        float4 p = P4[j * cm4 + q];
        acc[j] = fmaf(g.x, p.x, fmaf(g.y, p.y, fmaf(g.z, p.z, g.w * p.w)));
    }

    #pragma unroll
    for (int j = 0; j < ICc; ++j) {
        #pragma unroll
        for (int off = 32; off > 0; off >>= 1)
            acc[j] += __shfl_xor(acc[j], off, 64);
    }

    __shared__ float red[4][ICc];
    const int lane = threadIdx.x & 63, wid = threadIdx.x >> 6;
    if (lane == 0)
        for (int j = 0; j < ICc; ++j) red[wid][j] = acc[j];
    __syncthreads();

    if (threadIdx.x < ICc) {
        float sum = red[0][threadIdx.x] + red[1][threadIdx.x]
                  + red[2][threadIdx.x] + red[3][threadIdx.x];
        Apart[(((size_t)b * Sg + s) * ICc + i) * ICc + threadIdx.x] = sum;
    }
}

// ---------------------------------------------------------------------------
// Kernel 3: fused combine + apply, o-split 8.
// Prologue builds 8 rows of M'[o,c] = (W_w @ (A/N) @ theta_w)[o,c] + (o==c)
// and v[o] = (W_w @ (A/N) @ theta_b)[o] + W_b[o] from the gram partials.
// Main: out[b,o,n] = sum_c M'[o,c] x[b,c,n] + v[o].
// grid (Nn/512, B, 8) = 1024 blocks x 4 waves = 16 waves/CU; x re-read 8x
// (L2/L3-served), 16 acc regs/thread.
// ---------------------------------------------------------------------------
__global__ __launch_bounds__(256) void apply_kernel(
    const float* __restrict__ x, const float* __restrict__ Apart,
    const float* __restrict__ theta_w, const float* __restrict__ theta_b,
    const float* __restrict__ W_w,     const float* __restrict__ W_b,
    float* __restrict__ out)
{
    const int b  = blockIdx.y;
    const int ob = blockIdx.z * 8;

    __shared__ float sA[ICc * ICc];
    __shared__ float sT[8 * ICc];
    __shared__ float sM[8 * Cc];
    __shared__ float sv[8];

    const float* Ab = Apart + (size_t)b * Sg * ICc * ICc;
    for (int idx = threadIdx.x; idx < ICc * ICc; idx += 256) {
        float s = 0.f;
        #pragma unroll
        for (int k = 0; k < Sg; ++k) s += Ab[k * ICc * ICc + idx];
        sA[idx] = s;
    }
    __syncthreads();

    {   // sT[ol][j], 8*32 = 256 = blockDim
        const int ol = threadIdx.x >> 5, j = threadIdx.x & 31;
        const float* wr = W_w + (ob + ol) * ICc;
        float t = 0.f;
        #pragma unroll
        for (int i = 0; i < ICc; ++i) t = fmaf(wr[i], sA[i * ICc + j], t);
        sT[ol * ICc + j] = t;
    }
    __syncthreads();

    const float invN = 1.f / (float)Nn;
    for (int idx = threadIdx.x; idx < 8 * Cc; idx += 256) {
        const int ol = idx >> 6, c = idx & 63;
        float s = 0.f;
        #pragma unroll
        for (int j = 0; j < ICc; ++j) s = fmaf(sT[ol * ICc + j], theta_w[j * Cc + c], s);
        sM[idx] = s * invN + ((ob + ol) == c ? 1.f : 0.f);
    }
    if (threadIdx.x < 8) {
        float v = 0.f;
        #pragma unroll
        for (int j = 0; j < ICc; ++j) v = fmaf(sT[threadIdx.x * ICc + j], theta_b[j], v);
        sv[threadIdx.x] = v * invN + W_b[ob + threadIdx.x];
    }
    __syncthreads();

    const int n2 = blockIdx.x * 256 + threadIdx.x;     // float2 index
    const float2* xb  = (const float2*)(x + (size_t)b * Cc * Nn);
    float2*       ob2 = (float2*)(out + (size_t)b * Cc * Nn);

    float ax[8], ay[8];
    #pragma unroll
    for (int i = 0; i < 8; ++i) { ax[i] = sv[i]; ay[i] = sv[i]; }

    #pragma unroll 8
    for (int c = 0; c < Cc; ++c) {
        float2 xv = xb[c * (Nn / 2) + n2];
        #pragma unroll
        for (int i = 0; i < 8; ++i) {
            float w = sM[i * Cc + c];          // wave-broadcast, conflict-free
            ax[i] = fmaf(w, xv.x, ax[i]);
            ay[i] = fmaf(w, xv.y, ay[i]);
        }
    }

    #pragma unroll
    for (int i = 0; i < 8; ++i) {
        float2 o2; o2.x = ax[i]; o2.y = ay[i];
        ob2[(ob + i) * (Nn / 2) + n2] = o2;
    }
}

// ---------------------------------------------------------------------------
extern "C" void kernel_launch(void* const* d_in, const int* in_sizes, int n_in,
                              void* d_out, int out_size, void* d_ws, size_t ws_size,
                              hipStream_t stream) {
    const float* target    = (const float*)d_in[0];
    const float* ref       = (const float*)d_in[1];
    const float* ref_align = (const float*)d_in[2];
    const float* theta_w   = (const float*)d_in[3];
    const float* theta_b   = (const float*)d_in[4];
    const float* phi_w     = (const float*)d_in[5];
    const float* phi_b     = (const float*)d_in[6];
    const float* g_w       = (const float*)d_in[7];
    const float* g_b       = (const float*)d_in[8];
    const float* W_w       = (const float*)d_in[9];
    const float* W_b       = (const float*)d_in[10];
    float* out = (float*)d_out;

    // workspace (floats): P[B*IC*M] | G[B*IC*M] | Apart[B*Sg*IC*IC]
    float* ws    = (float*)d_ws;
    float* P     = ws;
    float* G     = P + (size_t)Bn * ICc * Mm;
    float* Apart = G + (size_t)Bn * ICc * Mm;

    conv_pool_kernel<<<dim3(Hp, Bn, 4), 256, 0, stream>>>(ref, ref_align,
                                                          phi_w, phi_b, g_w, g_b, P, G);
    gram_kernel<<<dim3(ICc, Bn, Sg), 256, 0, stream>>>(P, G, Apart);
    apply_kernel<<<dim3(Nn / 512, Bn, 8), 256, 0, stream>>>(target, Apart,
                                                            theta_w, theta_b,
                                                            W_w, W_b, out);
}